// Round 1
// baseline (773.071 us; speedup 1.0000x reference)
//
#include <hip/hip_runtime.h>

// h0[n][k] = (x[n]==0) ? 0 : emb[x[n]][k]   (padding_idx = 0)
__global__ __launch_bounds__(256) void embed_kernel(
    const int* __restrict__ x, const float* __restrict__ emb,
    float* __restrict__ h0, int n_nodes)
{
    int t = blockIdx.x * 256 + threadIdx.x;
    if (t >= n_nodes * 64) return;
    int n = t >> 6, k = t & 63;
    int xv = x[n];
    h0[t] = (xv == 0) ? 0.0f : emb[(size_t)xv * 64 + k];
}

__global__ __launch_bounds__(256) void hist_kernel(
    const int* __restrict__ ei, int* __restrict__ deg, int n_edges)
{
    int e = blockIdx.x * 256 + threadIdx.x;
    if (e >= n_edges) return;
    atomicAdd(&deg[ei[n_edges + e]], 1);   // dst row of edge_index
}

// exclusive prefix sum of deg[0..n) -> rowstart[0..n], single block
__global__ __launch_bounds__(1024) void scan_kernel(
    const int* __restrict__ deg, int* __restrict__ rowstart, int n)
{
    __shared__ int part[1024];
    int t = threadIdx.x;
    int ch = (n + 1023) >> 10;
    int lo = t * ch, hi = min(n, lo + ch);
    int s = 0;
    for (int i = lo; i < hi; ++i) s += deg[i];
    part[t] = s;
    __syncthreads();
    for (int off = 1; off < 1024; off <<= 1) {
        int v = (t >= off) ? part[t - off] : 0;
        __syncthreads();
        part[t] += v;
        __syncthreads();
    }
    int run = (t == 0) ? 0 : part[t - 1];
    for (int i = lo; i < hi; ++i) { rowstart[i] = run; run += deg[i]; }
    if (t == 1023) rowstart[n] = run;
}

__global__ __launch_bounds__(256) void scatter_kernel(
    const int* __restrict__ ei, const int* __restrict__ et,
    const int* __restrict__ rowstart, int* __restrict__ fill,
    int* __restrict__ esort, int n_edges)
{
    int e = blockIdx.x * 256 + threadIdx.x;
    if (e >= n_edges) return;
    int s = ei[e], d = ei[n_edges + e], r = et[e];
    int pos = rowstart[d] + atomicAdd(&fill[d], 1);
    esort[pos] = s | (r << 16);   // src < 65536, r < 4
}

// one wave per dst: per-relation mean of h[src]; writes means[dst][r*64+lane]
__global__ __launch_bounds__(256) void agg_kernel(
    const float* __restrict__ hin, const int* __restrict__ rowstart,
    const int* __restrict__ esort, float* __restrict__ means, int n_nodes)
{
    int wid = (blockIdx.x * 256 + threadIdx.x) >> 6;
    int lane = threadIdx.x & 63;
    if (wid >= n_nodes) return;
    int dst = wid;
    int s = rowstart[dst], e = rowstart[dst + 1];
    float a0 = 0.f, a1 = 0.f, a2 = 0.f;
    int c0 = 0, c1 = 0, c2 = 0;
    for (int i = s; i < e; ++i) {
        int p = esort[i];
        int src = p & 0xFFFF;
        int r = p >> 16;
        float v = hin[(size_t)src * 64 + lane];
        if (r == 0)      { a0 += v; c0++; }
        else if (r == 1) { a1 += v; c1++; }
        else             { a2 += v; c2++; }
    }
    float* m = means + (size_t)dst * 192;
    m[lane]       = a0 / (float)max(c0, 1);
    m[64 + lane]  = a1 / (float)max(c1, 1);
    m[128 + lane] = a2 / (float)max(c2, 1);
}

// lane-per-node: out[n][j] = relu( b[j] + sum_k h[n][k]*Wroot[k][j]
//                                 + sum_{r,k} mean_r[n][k]*Wrel[r][k][j] )
__global__ __launch_bounds__(256) void transform_kernel(
    const float* __restrict__ hin, const float* __restrict__ means,
    const float* __restrict__ wroot, const float* __restrict__ wrel,
    const float* __restrict__ bias, float* __restrict__ hout, int n_nodes)
{
    int n = blockIdx.x * 256 + threadIdx.x;
    if (n >= n_nodes) return;
    float acc[64];
#pragma unroll
    for (int j = 0; j < 64; ++j) acc[j] = bias[j];

    const float* hv = hin + (size_t)n * 64;
#pragma unroll 4
    for (int k = 0; k < 64; ++k) {
        float v = hv[k];
        const float* wr = wroot + k * 64;   // wave-uniform -> s_load
#pragma unroll
        for (int j = 0; j < 64; ++j) acc[j] = fmaf(v, wr[j], acc[j]);
    }
    const float* mv = means + (size_t)n * 192;
#pragma unroll 4
    for (int k = 0; k < 192; ++k) {
        float v = mv[k];
        const float* wr = wrel + k * 64;    // wrel[3][64][64] flat, row = k
#pragma unroll
        for (int j = 0; j < 64; ++j) acc[j] = fmaf(v, wr[j], acc[j]);
    }
    float* o = hout + (size_t)n * 64;
#pragma unroll
    for (int j = 0; j < 64; ++j) o[j] = fmaxf(acc[j], 0.0f);
}

// wave per graph: batch is sorted -> binary-search bounds, mean, then 64->2 head
__global__ __launch_bounds__(256) void pool_kernel(
    const float* __restrict__ h2, const int* __restrict__ batch,
    const float* __restrict__ linw, const float* __restrict__ linb,
    float* __restrict__ out, int n_nodes, int n_graphs)
{
    int wid = (blockIdx.x * 256 + threadIdx.x) >> 6;
    int lane = threadIdx.x & 63;
    if (wid >= n_graphs) return;
    int g = wid;
    int lo = 0, hi = n_nodes;
    while (lo < hi) { int mid = (lo + hi) >> 1; if (batch[mid] < g) lo = mid + 1; else hi = mid; }
    int s = lo;
    lo = 0; hi = n_nodes;
    while (lo < hi) { int mid = (lo + hi) >> 1; if (batch[mid] < g + 1) lo = mid + 1; else hi = mid; }
    int e = lo;
    float sum = 0.f;
    for (int n = s; n < e; ++n) sum += h2[(size_t)n * 64 + lane];
    float mean = sum / (float)max(e - s, 1);
    float d0 = mean * linw[lane * 2 + 0];
    float d1 = mean * linw[lane * 2 + 1];
    for (int off = 32; off > 0; off >>= 1) {
        d0 += __shfl_down(d0, off);
        d1 += __shfl_down(d1, off);
    }
    if (lane == 0) {
        out[g * 2 + 0] = d0 + linb[0];
        out[g * 2 + 1] = d1 + linb[1];
    }
}

extern "C" void kernel_launch(void* const* d_in, const int* in_sizes, int n_in,
                              void* d_out, int out_size, void* d_ws, size_t ws_size,
                              hipStream_t stream)
{
    const int*   x      = (const int*)d_in[0];
    const int*   ei     = (const int*)d_in[1];
    const int*   et     = (const int*)d_in[2];
    const int*   batch  = (const int*)d_in[3];
    const float* emb    = (const float*)d_in[4];
    const float* w1rel  = (const float*)d_in[5];
    const float* w1root = (const float*)d_in[6];
    const float* b1     = (const float*)d_in[7];
    const float* w2rel  = (const float*)d_in[8];
    const float* w2root = (const float*)d_in[9];
    const float* b2     = (const float*)d_in[10];
    const float* linw   = (const float*)d_in[11];
    const float* linb   = (const float*)d_in[12];
    float* out = (float*)d_out;

    const int N = in_sizes[0];        // 50000
    const int E = in_sizes[2];        // 1250000 (edge_type length)
    const int G = out_size / 2;       // 512

    // workspace layout (~70 MB)
    float* hA       = (float*)d_ws;                    // [N][64]  h0, later h2
    float* hB       = hA + (size_t)N * 64;             // [N][64]  h1
    float* means    = hB + (size_t)N * 64;             // [N][192]
    int*   esort    = (int*)(means + (size_t)N * 192); // [E]
    int*   rowstart = esort + E;                       // [N+1]
    int*   deg      = rowstart + (N + 1);              // [N]   (zeroed)
    int*   fill     = deg + N;                         // [N]   (zeroed)

    hipMemsetAsync(deg, 0, (size_t)2 * N * sizeof(int), stream);

    embed_kernel<<<(N * 64 + 255) / 256, 256, 0, stream>>>(x, emb, hA, N);
    hist_kernel<<<(E + 255) / 256, 256, 0, stream>>>(ei, deg, E);
    scan_kernel<<<1, 1024, 0, stream>>>(deg, rowstart, N);
    scatter_kernel<<<(E + 255) / 256, 256, 0, stream>>>(ei, et, rowstart, fill, esort, E);

    int aggBlocks = (N * 64 + 255) / 256;   // one wave per dst
    agg_kernel<<<aggBlocks, 256, 0, stream>>>(hA, rowstart, esort, means, N);
    transform_kernel<<<(N + 255) / 256, 256, 0, stream>>>(hA, means, w1root, w1rel, b1, hB, N);
    agg_kernel<<<aggBlocks, 256, 0, stream>>>(hB, rowstart, esort, means, N);
    transform_kernel<<<(N + 255) / 256, 256, 0, stream>>>(hB, means, w2root, w2rel, b2, hA, N);

    pool_kernel<<<(G * 64 + 255) / 256, 256, 0, stream>>>(hA, batch, linw, linb, out, N, G);
}

// Round 2
// 675.913 us; speedup vs baseline: 1.1437x; 1.1437x over previous
//
#include <hip/hip_runtime.h>

// h0[n][k] = (x[n]==0) ? 0 : emb[x[n]][k]   (padding_idx = 0), float4 per thread
__global__ __launch_bounds__(256) void embed_kernel(
    const int* __restrict__ x, const float* __restrict__ emb,
    float* __restrict__ h0, int n_nodes)
{
    int t = blockIdx.x * 256 + threadIdx.x;
    if (t >= n_nodes * 16) return;
    int n = t >> 4, q = t & 15;
    int xv = x[n];
    float4 v = {0.f, 0.f, 0.f, 0.f};
    if (xv != 0) v = *(const float4*)(emb + (size_t)xv * 64 + q * 4);
    *(float4*)(h0 + (size_t)n * 64 + q * 4) = v;
}

__global__ __launch_bounds__(256) void hist_kernel(
    const int* __restrict__ ei, int* __restrict__ deg, int n_edges)
{
    int e = blockIdx.x * 256 + threadIdx.x;
    if (e >= n_edges) return;
    atomicAdd(&deg[ei[n_edges + e]], 1);   // dst row of edge_index
}

// exclusive prefix sum of deg[0..n) -> rowstart[0..n], single block
__global__ __launch_bounds__(1024) void scan_kernel(
    const int* __restrict__ deg, int* __restrict__ rowstart, int n)
{
    __shared__ int part[1024];
    int t = threadIdx.x;
    int ch = (n + 1023) >> 10;
    int lo = t * ch, hi = min(n, lo + ch);
    int s = 0;
    for (int i = lo; i < hi; ++i) s += deg[i];
    part[t] = s;
    __syncthreads();
    for (int off = 1; off < 1024; off <<= 1) {
        int v = (t >= off) ? part[t - off] : 0;
        __syncthreads();
        part[t] += v;
        __syncthreads();
    }
    int run = (t == 0) ? 0 : part[t - 1];
    for (int i = lo; i < hi; ++i) { rowstart[i] = run; run += deg[i]; }
    if (t == 1023) rowstart[n] = run;
}

__global__ __launch_bounds__(256) void scatter_kernel(
    const int* __restrict__ ei, const int* __restrict__ et,
    const int* __restrict__ rowstart, int* __restrict__ fill,
    int* __restrict__ esort, int n_edges)
{
    int e = blockIdx.x * 256 + threadIdx.x;
    if (e >= n_edges) return;
    int s = ei[e], d = ei[n_edges + e], r = et[e];
    int pos = rowstart[d] + atomicAdd(&fill[d], 1);
    esort[pos] = s | (r << 16);   // src < 65536, r < 4
}

// one wave per dst. Quarter-wave q handles edge s+q, s+q+4, ... ; each lane
// holds a float4 channel-quad (c = lane&15). 4 row-loads in flight per wave.
// Cross-quarter shfl_xor reduction at the end; writes per-relation means.
__global__ __launch_bounds__(256) void agg_kernel(
    const float* __restrict__ hin, const int* __restrict__ rowstart,
    const int* __restrict__ esort, float* __restrict__ means, int n_nodes)
{
    int wid = (blockIdx.x * 256 + threadIdx.x) >> 6;
    int lane = threadIdx.x & 63;
    if (wid >= n_nodes) return;
    int q = lane >> 4;       // edge slot within group of 4
    int c = lane & 15;       // channel quad
    int s = rowstart[wid], e = rowstart[wid + 1];

    float a0x=0.f,a0y=0.f,a0z=0.f,a0w=0.f, c0=0.f;
    float a1x=0.f,a1y=0.f,a1z=0.f,a1w=0.f, c1=0.f;
    float a2x=0.f,a2y=0.f,a2z=0.f,a2w=0.f, c2=0.f;

    for (int i = s + q; i < e; i += 4) {
        int p = esort[i];
        int src = p & 0xFFFF;
        int r = p >> 16;
        float4 v = *(const float4*)(hin + (size_t)src * 64 + c * 4);
        float m0 = (r == 0) ? 1.f : 0.f;
        float m1 = (r == 1) ? 1.f : 0.f;
        float m2 = (r == 2) ? 1.f : 0.f;
        a0x = fmaf(m0, v.x, a0x); a0y = fmaf(m0, v.y, a0y);
        a0z = fmaf(m0, v.z, a0z); a0w = fmaf(m0, v.w, a0w); c0 += m0;
        a1x = fmaf(m1, v.x, a1x); a1y = fmaf(m1, v.y, a1y);
        a1z = fmaf(m1, v.z, a1z); a1w = fmaf(m1, v.w, a1w); c1 += m1;
        a2x = fmaf(m2, v.x, a2x); a2y = fmaf(m2, v.y, a2y);
        a2z = fmaf(m2, v.z, a2z); a2w = fmaf(m2, v.w, a2w); c2 += m2;
    }
#pragma unroll
    for (int off = 16; off < 64; off <<= 1) {
        a0x += __shfl_xor(a0x, off); a0y += __shfl_xor(a0y, off);
        a0z += __shfl_xor(a0z, off); a0w += __shfl_xor(a0w, off);
        a1x += __shfl_xor(a1x, off); a1y += __shfl_xor(a1y, off);
        a1z += __shfl_xor(a1z, off); a1w += __shfl_xor(a1w, off);
        a2x += __shfl_xor(a2x, off); a2y += __shfl_xor(a2y, off);
        a2z += __shfl_xor(a2z, off); a2w += __shfl_xor(a2w, off);
        c0 += __shfl_xor(c0, off); c1 += __shfl_xor(c1, off);
        c2 += __shfl_xor(c2, off);
    }
    if (q < 3) {
        float ax = (q == 0) ? a0x : (q == 1) ? a1x : a2x;
        float ay = (q == 0) ? a0y : (q == 1) ? a1y : a2y;
        float az = (q == 0) ? a0z : (q == 1) ? a1z : a2z;
        float aw = (q == 0) ? a0w : (q == 1) ? a1w : a2w;
        float cc = (q == 0) ? c0  : (q == 1) ? c1  : c2;
        float inv = 1.f / fmaxf(cc, 1.f);
        float4 m;
        m.x = ax * inv; m.y = ay * inv; m.z = az * inv; m.w = aw * inv;
        *(float4*)(means + (size_t)wid * 192 + q * 64 + c * 4) = m;
    }
}

// thread = (node, j-quad): out[n][4q..4q+3] = relu(b + h@Wroot + sum_r mean_r@Wr)
__global__ __launch_bounds__(256) void transform_kernel(
    const float* __restrict__ hin, const float* __restrict__ means,
    const float* __restrict__ wroot, const float* __restrict__ wrel,
    const float* __restrict__ bias, float* __restrict__ hout, int n_nodes)
{
    int t = blockIdx.x * 256 + threadIdx.x;
    int n = t >> 4, q = t & 15;
    if (n >= n_nodes) return;
    float4 b = *(const float4*)(bias + q * 4);
    float acc0 = b.x, acc1 = b.y, acc2 = b.z, acc3 = b.w;

    const float* hv = hin + (size_t)n * 64;
#pragma unroll 4
    for (int k4 = 0; k4 < 16; ++k4) {
        float4 v = *(const float4*)(hv + k4 * 4);
        float vv[4] = {v.x, v.y, v.z, v.w};
#pragma unroll
        for (int i = 0; i < 4; ++i) {
            float4 w = *(const float4*)(wroot + (size_t)(k4 * 4 + i) * 64 + q * 4);
            acc0 = fmaf(vv[i], w.x, acc0);
            acc1 = fmaf(vv[i], w.y, acc1);
            acc2 = fmaf(vv[i], w.z, acc2);
            acc3 = fmaf(vv[i], w.w, acc3);
        }
    }
    const float* mv = means + (size_t)n * 192;
#pragma unroll 4
    for (int k4 = 0; k4 < 48; ++k4) {
        float4 v = *(const float4*)(mv + k4 * 4);
        float vv[4] = {v.x, v.y, v.z, v.w};
#pragma unroll
        for (int i = 0; i < 4; ++i) {
            float4 w = *(const float4*)(wrel + (size_t)(k4 * 4 + i) * 64 + q * 4);
            acc0 = fmaf(vv[i], w.x, acc0);
            acc1 = fmaf(vv[i], w.y, acc1);
            acc2 = fmaf(vv[i], w.z, acc2);
            acc3 = fmaf(vv[i], w.w, acc3);
        }
    }
    float4 o;
    o.x = fmaxf(acc0, 0.f); o.y = fmaxf(acc1, 0.f);
    o.z = fmaxf(acc2, 0.f); o.w = fmaxf(acc3, 0.f);
    *(float4*)(hout + (size_t)n * 64 + q * 4) = o;
}

// wave per graph: batch is sorted -> binary-search bounds, mean, then 64->2 head
__global__ __launch_bounds__(256) void pool_kernel(
    const float* __restrict__ h2, const int* __restrict__ batch,
    const float* __restrict__ linw, const float* __restrict__ linb,
    float* __restrict__ out, int n_nodes, int n_graphs)
{
    int wid = (blockIdx.x * 256 + threadIdx.x) >> 6;
    int lane = threadIdx.x & 63;
    if (wid >= n_graphs) return;
    int g = wid;
    int lo = 0, hi = n_nodes;
    while (lo < hi) { int mid = (lo + hi) >> 1; if (batch[mid] < g) lo = mid + 1; else hi = mid; }
    int s = lo;
    lo = 0; hi = n_nodes;
    while (lo < hi) { int mid = (lo + hi) >> 1; if (batch[mid] < g + 1) lo = mid + 1; else hi = mid; }
    int e = lo;
    float sum = 0.f;
    for (int n = s; n < e; ++n) sum += h2[(size_t)n * 64 + lane];
    float mean = sum / (float)max(e - s, 1);
    float d0 = mean * linw[lane * 2 + 0];
    float d1 = mean * linw[lane * 2 + 1];
    for (int off = 32; off > 0; off >>= 1) {
        d0 += __shfl_down(d0, off);
        d1 += __shfl_down(d1, off);
    }
    if (lane == 0) {
        out[g * 2 + 0] = d0 + linb[0];
        out[g * 2 + 1] = d1 + linb[1];
    }
}

extern "C" void kernel_launch(void* const* d_in, const int* in_sizes, int n_in,
                              void* d_out, int out_size, void* d_ws, size_t ws_size,
                              hipStream_t stream)
{
    const int*   x      = (const int*)d_in[0];
    const int*   ei     = (const int*)d_in[1];
    const int*   et     = (const int*)d_in[2];
    const int*   batch  = (const int*)d_in[3];
    const float* emb    = (const float*)d_in[4];
    const float* w1rel  = (const float*)d_in[5];
    const float* w1root = (const float*)d_in[6];
    const float* b1     = (const float*)d_in[7];
    const float* w2rel  = (const float*)d_in[8];
    const float* w2root = (const float*)d_in[9];
    const float* b2     = (const float*)d_in[10];
    const float* linw   = (const float*)d_in[11];
    const float* linb   = (const float*)d_in[12];
    float* out = (float*)d_out;

    const int N = in_sizes[0];        // 50000
    const int E = in_sizes[2];        // 1250000
    const int G = out_size / 2;       // 512

    // workspace layout (~70 MB)
    float* hA       = (float*)d_ws;                    // [N][64]  h0, later h2
    float* hB       = hA + (size_t)N * 64;             // [N][64]  h1
    float* means    = hB + (size_t)N * 64;             // [N][192]
    int*   esort    = (int*)(means + (size_t)N * 192); // [E]
    int*   rowstart = esort + E;                       // [N+1]
    int*   deg      = rowstart + (N + 1);              // [N]   (zeroed)
    int*   fill     = deg + N;                         // [N]   (zeroed)

    hipMemsetAsync(deg, 0, (size_t)2 * N * sizeof(int), stream);

    embed_kernel<<<(N * 16 + 255) / 256, 256, 0, stream>>>(x, emb, hA, N);
    hist_kernel<<<(E + 255) / 256, 256, 0, stream>>>(ei, deg, E);
    scan_kernel<<<1, 1024, 0, stream>>>(deg, rowstart, N);
    scatter_kernel<<<(E + 255) / 256, 256, 0, stream>>>(ei, et, rowstart, fill, esort, E);

    int aggBlocks = (N * 64 + 255) / 256;   // one wave per dst
    agg_kernel<<<aggBlocks, 256, 0, stream>>>(hA, rowstart, esort, means, N);
    transform_kernel<<<(N * 16 + 255) / 256, 256, 0, stream>>>(hA, means, w1root, w1rel, b1, hB, N);
    agg_kernel<<<aggBlocks, 256, 0, stream>>>(hB, rowstart, esort, means, N);
    transform_kernel<<<(N * 16 + 255) / 256, 256, 0, stream>>>(hB, means, w2root, w2rel, b2, hA, N);

    pool_kernel<<<(G * 64 + 255) / 256, 256, 0, stream>>>(hA, batch, linw, linb, out, N, G);
}

// Round 3
// 541.357 us; speedup vs baseline: 1.4280x; 1.2486x over previous
//
#include <hip/hip_runtime.h>

// h0[n][k] = (x[n]==0) ? 0 : emb[x[n]][k]   (padding_idx = 0), float4 per thread
__global__ __launch_bounds__(256) void embed_kernel(
    const int* __restrict__ x, const float* __restrict__ emb,
    float* __restrict__ h0, int n_nodes)
{
    int t = blockIdx.x * 256 + threadIdx.x;
    if (t >= n_nodes * 16) return;
    int n = t >> 4, q = t & 15;
    int xv = x[n];
    float4 v = {0.f, 0.f, 0.f, 0.f};
    if (xv != 0) v = *(const float4*)(emb + (size_t)xv * 64 + q * 4);
    *(float4*)(h0 + (size_t)n * 64 + q * 4) = v;
}

__global__ __launch_bounds__(256) void hist_kernel(
    const int* __restrict__ ei, int* __restrict__ deg, int n_edges)
{
    int e = blockIdx.x * 256 + threadIdx.x;
    if (e >= n_edges) return;
    atomicAdd(&deg[ei[n_edges + e]], 1);   // dst row of edge_index
}

// exclusive prefix sum of deg[0..n) -> rowstart[0..n], single block
__global__ __launch_bounds__(1024) void scan_kernel(
    const int* __restrict__ deg, int* __restrict__ rowstart, int n)
{
    __shared__ int part[1024];
    int t = threadIdx.x;
    int ch = (n + 1023) >> 10;
    int lo = t * ch, hi = min(n, lo + ch);
    int s = 0;
    for (int i = lo; i < hi; ++i) s += deg[i];
    part[t] = s;
    __syncthreads();
    for (int off = 1; off < 1024; off <<= 1) {
        int v = (t >= off) ? part[t - off] : 0;
        __syncthreads();
        part[t] += v;
        __syncthreads();
    }
    int run = (t == 0) ? 0 : part[t - 1];
    for (int i = lo; i < hi; ++i) { rowstart[i] = run; run += deg[i]; }
    if (t == 1023) rowstart[n] = run;
}

__global__ __launch_bounds__(256) void scatter_kernel(
    const int* __restrict__ ei, const int* __restrict__ et,
    const int* __restrict__ rowstart, int* __restrict__ fill,
    int* __restrict__ esort, int n_edges)
{
    int e = blockIdx.x * 256 + threadIdx.x;
    if (e >= n_edges) return;
    int s = ei[e], d = ei[n_edges + e], r = et[e];
    int pos = rowstart[d] + atomicAdd(&fill[d], 1);
    esort[pos] = s | (r << 16);   // src < 65536, r < 4
}

// one wave per dst. Quarter-wave q handles edge s+q, s+q+4, ... ; each lane
// holds a float4 channel-quad (c = lane&15). 4 row-loads in flight per wave.
__global__ __launch_bounds__(256) void agg_kernel(
    const float* __restrict__ hin, const int* __restrict__ rowstart,
    const int* __restrict__ esort, float* __restrict__ means, int n_nodes)
{
    int wid = (blockIdx.x * 256 + threadIdx.x) >> 6;
    int lane = threadIdx.x & 63;
    if (wid >= n_nodes) return;
    int q = lane >> 4;       // edge slot within group of 4
    int c = lane & 15;       // channel quad
    int s = rowstart[wid], e = rowstart[wid + 1];

    float a0x=0.f,a0y=0.f,a0z=0.f,a0w=0.f, c0=0.f;
    float a1x=0.f,a1y=0.f,a1z=0.f,a1w=0.f, c1=0.f;
    float a2x=0.f,a2y=0.f,a2z=0.f,a2w=0.f, c2=0.f;

    for (int i = s + q; i < e; i += 4) {
        int p = esort[i];
        int src = p & 0xFFFF;
        int r = p >> 16;
        float4 v = *(const float4*)(hin + (size_t)src * 64 + c * 4);
        float m0 = (r == 0) ? 1.f : 0.f;
        float m1 = (r == 1) ? 1.f : 0.f;
        float m2 = (r == 2) ? 1.f : 0.f;
        a0x = fmaf(m0, v.x, a0x); a0y = fmaf(m0, v.y, a0y);
        a0z = fmaf(m0, v.z, a0z); a0w = fmaf(m0, v.w, a0w); c0 += m0;
        a1x = fmaf(m1, v.x, a1x); a1y = fmaf(m1, v.y, a1y);
        a1z = fmaf(m1, v.z, a1z); a1w = fmaf(m1, v.w, a1w); c1 += m1;
        a2x = fmaf(m2, v.x, a2x); a2y = fmaf(m2, v.y, a2y);
        a2z = fmaf(m2, v.z, a2z); a2w = fmaf(m2, v.w, a2w); c2 += m2;
    }
#pragma unroll
    for (int off = 16; off < 64; off <<= 1) {
        a0x += __shfl_xor(a0x, off); a0y += __shfl_xor(a0y, off);
        a0z += __shfl_xor(a0z, off); a0w += __shfl_xor(a0w, off);
        a1x += __shfl_xor(a1x, off); a1y += __shfl_xor(a1y, off);
        a1z += __shfl_xor(a1z, off); a1w += __shfl_xor(a1w, off);
        a2x += __shfl_xor(a2x, off); a2y += __shfl_xor(a2y, off);
        a2z += __shfl_xor(a2z, off); a2w += __shfl_xor(a2w, off);
        c0 += __shfl_xor(c0, off); c1 += __shfl_xor(c1, off);
        c2 += __shfl_xor(c2, off);
    }
    if (q < 3) {
        float ax = (q == 0) ? a0x : (q == 1) ? a1x : a2x;
        float ay = (q == 0) ? a0y : (q == 1) ? a1y : a2y;
        float az = (q == 0) ? a0z : (q == 1) ? a1z : a2z;
        float aw = (q == 0) ? a0w : (q == 1) ? a1w : a2w;
        float cc = (q == 0) ? c0  : (q == 1) ? c1  : c2;
        float inv = 1.f / fmaxf(cc, 1.f);
        float4 m;
        m.x = ax * inv; m.y = ay * inv; m.z = az * inv; m.w = aw * inv;
        *(float4*)(means + (size_t)wid * 192 + q * 64 + c * 4) = m;
    }
}

// thread = (node, j-quad). Combined weight W[256][64] (wroot rows 0..63,
// wrel rows 64..255) staged in LDS (64 KB) once per block; inner loop reads
// W via ds_read_b128 (16 unique addrs/wave, 4-lane broadcast, conflict-free)
// and v via global float4 (16-lane same-address broadcast, L1-hit).
__global__ __launch_bounds__(256) void transform_kernel(
    const float* __restrict__ hin, const float* __restrict__ means,
    const float* __restrict__ wroot, const float* __restrict__ wrel,
    const float* __restrict__ bias, float* __restrict__ hout, int n_nodes)
{
    __shared__ float wsh[256 * 64];   // 64 KB -> 2 blocks/CU
    int t = threadIdx.x;
    // stage: wroot (4096 floats) + wrel (12288 floats), coalesced float4 copies
    {
        const float4* src = (const float4*)wroot;
        float4* dst = (float4*)wsh;
#pragma unroll
        for (int i = 0; i < 4; ++i) dst[t + i * 256] = src[t + i * 256];
        src = (const float4*)wrel;
        dst = (float4*)(wsh + 4096);
#pragma unroll
        for (int i = 0; i < 12; ++i) dst[t + i * 256] = src[t + i * 256];
    }
    __syncthreads();

    int gt = blockIdx.x * 256 + t;
    int n = gt >> 4, q = gt & 15;
    if (n >= n_nodes) return;

    float4 b = *(const float4*)(bias + q * 4);
    float acc0 = b.x, acc1 = b.y, acc2 = b.z, acc3 = b.w;

    const float* hv = hin + (size_t)n * 64;
#pragma unroll 4
    for (int k4 = 0; k4 < 16; ++k4) {
        float4 v = *(const float4*)(hv + k4 * 4);
        float vv[4] = {v.x, v.y, v.z, v.w};
#pragma unroll
        for (int i = 0; i < 4; ++i) {
            float4 w = *(const float4*)(wsh + (k4 * 4 + i) * 64 + q * 4);
            acc0 = fmaf(vv[i], w.x, acc0);
            acc1 = fmaf(vv[i], w.y, acc1);
            acc2 = fmaf(vv[i], w.z, acc2);
            acc3 = fmaf(vv[i], w.w, acc3);
        }
    }
    const float* mv = means + (size_t)n * 192;
#pragma unroll 4
    for (int k4 = 0; k4 < 48; ++k4) {
        float4 v = *(const float4*)(mv + k4 * 4);
        float vv[4] = {v.x, v.y, v.z, v.w};
#pragma unroll
        for (int i = 0; i < 4; ++i) {
            float4 w = *(const float4*)(wsh + (64 + k4 * 4 + i) * 64 + q * 4);
            acc0 = fmaf(vv[i], w.x, acc0);
            acc1 = fmaf(vv[i], w.y, acc1);
            acc2 = fmaf(vv[i], w.z, acc2);
            acc3 = fmaf(vv[i], w.w, acc3);
        }
    }
    float4 o;
    o.x = fmaxf(acc0, 0.f); o.y = fmaxf(acc1, 0.f);
    o.z = fmaxf(acc2, 0.f); o.w = fmaxf(acc3, 0.f);
    *(float4*)(hout + (size_t)n * 64 + q * 4) = o;
}

// wave per graph: batch is sorted -> binary-search bounds, mean, then 64->2 head
__global__ __launch_bounds__(256) void pool_kernel(
    const float* __restrict__ h2, const int* __restrict__ batch,
    const float* __restrict__ linw, const float* __restrict__ linb,
    float* __restrict__ out, int n_nodes, int n_graphs)
{
    int wid = (blockIdx.x * 256 + threadIdx.x) >> 6;
    int lane = threadIdx.x & 63;
    if (wid >= n_graphs) return;
    int g = wid;
    int lo = 0, hi = n_nodes;
    while (lo < hi) { int mid = (lo + hi) >> 1; if (batch[mid] < g) lo = mid + 1; else hi = mid; }
    int s = lo;
    lo = 0; hi = n_nodes;
    while (lo < hi) { int mid = (lo + hi) >> 1; if (batch[mid] < g + 1) lo = mid + 1; else hi = mid; }
    int e = lo;
    float sum = 0.f;
    for (int n = s; n < e; ++n) sum += h2[(size_t)n * 64 + lane];
    float mean = sum / (float)max(e - s, 1);
    float d0 = mean * linw[lane * 2 + 0];
    float d1 = mean * linw[lane * 2 + 1];
    for (int off = 32; off > 0; off >>= 1) {
        d0 += __shfl_down(d0, off);
        d1 += __shfl_down(d1, off);
    }
    if (lane == 0) {
        out[g * 2 + 0] = d0 + linb[0];
        out[g * 2 + 1] = d1 + linb[1];
    }
}

extern "C" void kernel_launch(void* const* d_in, const int* in_sizes, int n_in,
                              void* d_out, int out_size, void* d_ws, size_t ws_size,
                              hipStream_t stream)
{
    const int*   x      = (const int*)d_in[0];
    const int*   ei     = (const int*)d_in[1];
    const int*   et     = (const int*)d_in[2];
    const int*   batch  = (const int*)d_in[3];
    const float* emb    = (const float*)d_in[4];
    const float* w1rel  = (const float*)d_in[5];
    const float* w1root = (const float*)d_in[6];
    const float* b1     = (const float*)d_in[7];
    const float* w2rel  = (const float*)d_in[8];
    const float* w2root = (const float*)d_in[9];
    const float* b2     = (const float*)d_in[10];
    const float* linw   = (const float*)d_in[11];
    const float* linb   = (const float*)d_in[12];
    float* out = (float*)d_out;

    const int N = in_sizes[0];        // 50000
    const int E = in_sizes[2];        // 1250000
    const int G = out_size / 2;       // 512

    // workspace layout (~70 MB)
    float* hA       = (float*)d_ws;                    // [N][64]  h0, later h2
    float* hB       = hA + (size_t)N * 64;             // [N][64]  h1
    float* means    = hB + (size_t)N * 64;             // [N][192]
    int*   esort    = (int*)(means + (size_t)N * 192); // [E]
    int*   rowstart = esort + E;                       // [N+1]
    int*   deg      = rowstart + (N + 1);              // [N]   (zeroed)
    int*   fill     = deg + N;                         // [N]   (zeroed)

    hipMemsetAsync(deg, 0, (size_t)2 * N * sizeof(int), stream);

    embed_kernel<<<(N * 16 + 255) / 256, 256, 0, stream>>>(x, emb, hA, N);
    hist_kernel<<<(E + 255) / 256, 256, 0, stream>>>(ei, deg, E);
    scan_kernel<<<1, 1024, 0, stream>>>(deg, rowstart, N);
    scatter_kernel<<<(E + 255) / 256, 256, 0, stream>>>(ei, et, rowstart, fill, esort, E);

    int aggBlocks = (N * 64 + 255) / 256;   // one wave per dst
    agg_kernel<<<aggBlocks, 256, 0, stream>>>(hA, rowstart, esort, means, N);
    transform_kernel<<<(N * 16 + 255) / 256, 256, 0, stream>>>(hA, means, w1root, w1rel, b1, hB, N);
    agg_kernel<<<aggBlocks, 256, 0, stream>>>(hB, rowstart, esort, means, N);
    transform_kernel<<<(N * 16 + 255) / 256, 256, 0, stream>>>(hB, means, w2root, w2rel, b2, hA, N);

    pool_kernel<<<(G * 64 + 255) / 256, 256, 0, stream>>>(hA, batch, linw, linb, out, N, G);
}

// Round 4
// 386.804 us; speedup vs baseline: 1.9986x; 1.3996x over previous
//
#include <hip/hip_runtime.h>

// h0[n][k] = (x[n]==0) ? 0 : emb[x[n]][k]   (padding_idx = 0), float4 per thread
__global__ __launch_bounds__(256) void embed_kernel(
    const int* __restrict__ x, const float* __restrict__ emb,
    float* __restrict__ h0, int n_nodes)
{
    int t = blockIdx.x * 256 + threadIdx.x;
    if (t >= n_nodes * 16) return;
    int n = t >> 4, q = t & 15;
    int xv = x[n];
    float4 v = {0.f, 0.f, 0.f, 0.f};
    if (xv != 0) v = *(const float4*)(emb + (size_t)xv * 64 + q * 4);
    *(float4*)(h0 + (size_t)n * 64 + q * 4) = v;
}

// ---- CSR build: two-level bucket sort (bucket = dst>>7, 128 dsts/bucket) ----

// per-block LDS histogram of dst buckets -> global bucket_count
__global__ __launch_bounds__(256) void bucket_count_kernel(
    const int* __restrict__ ei, int* __restrict__ bucket_count,
    int n_edges, int n_bkt, int per_block)
{
    __shared__ int cnt[512];
    int t = threadIdx.x;
    for (int i = t; i < n_bkt; i += 256) cnt[i] = 0;
    __syncthreads();
    int lo = blockIdx.x * per_block;
    int hi = min(n_edges, lo + per_block);
    for (int e = lo + t; e < hi; e += 256)
        atomicAdd(&cnt[ei[n_edges + e] >> 7], 1);
    __syncthreads();
    for (int i = t; i < n_bkt; i += 256)
        if (cnt[i]) atomicAdd(&bucket_count[i], cnt[i]);
}

// single block: exclusive scan of bucket_count -> bucket_start[0..n_bkt]
__global__ __launch_bounds__(512) void scan_buckets_kernel(
    const int* __restrict__ bucket_count, int* __restrict__ bucket_start,
    int* __restrict__ rowstart, int n_bkt, int n_edges, int n_nodes)
{
    __shared__ int part[512];
    int t = threadIdx.x;
    part[t] = (t < n_bkt) ? bucket_count[t] : 0;
    __syncthreads();
    for (int off = 1; off < 512; off <<= 1) {
        int v = (t >= off) ? part[t - off] : 0;
        __syncthreads();
        part[t] += v;
        __syncthreads();
    }
    if (t == 0) { bucket_start[0] = 0; rowstart[n_nodes] = n_edges; }
    if (t < n_bkt) bucket_start[t + 1] = part[t];
}

// 8192 edges/block: LDS count per bucket, reserve a contiguous run per
// (block,bucket) with ONE global atomic, write packed entries into the run.
// Entry: src(16) | type(2)<<16 | (dst&127)<<18. Writes are block-private
// dense runs -> single-XCD line ownership, no cross-XCD write thrash.
__global__ __launch_bounds__(256) void bucket_scatter_kernel(
    const int* __restrict__ ei, const int* __restrict__ et,
    const int* __restrict__ bucket_start, int* __restrict__ bucket_fill,
    int* __restrict__ esort, int n_edges, int n_bkt)
{
    __shared__ int cnt[512], gbase[512], fill2[512];
    const int EPT = 32;
    int t = threadIdx.x;
    int base = blockIdx.x * 256 * EPT;
    for (int i = t; i < n_bkt; i += 256) { cnt[i] = 0; fill2[i] = 0; }
    __syncthreads();
    int pay[EPT], bk[EPT];
#pragma unroll
    for (int i = 0; i < EPT; ++i) {
        int e = base + i * 256 + t;
        bk[i] = -1;
        if (e < n_edges) {
            int s = ei[e], d = ei[n_edges + e], r = et[e];
            int b = d >> 7;
            pay[i] = s | (r << 16) | ((d & 127) << 18);
            bk[i] = b;
            atomicAdd(&cnt[b], 1);
        }
    }
    __syncthreads();
    for (int i = t; i < n_bkt; i += 256)
        if (cnt[i]) gbase[i] = bucket_start[i] + atomicAdd(&bucket_fill[i], cnt[i]);
    __syncthreads();
#pragma unroll
    for (int i = 0; i < EPT; ++i) {
        if (bk[i] >= 0) {
            int pos = gbase[bk[i]] + atomicAdd(&fill2[bk[i]], 1);
            esort[pos] = pay[i];
        }
    }
}

// one block per bucket: copy bucket to scratch, LDS counting-sort by
// dst-within-bucket (128 bins), write back in place fully dst-sorted,
// and emit rowstart[dst] from the scan.
__global__ __launch_bounds__(256) void bucket_sort_kernel(
    const int* __restrict__ bucket_start, int* __restrict__ esort,
    int* __restrict__ scratch, int* __restrict__ rowstart, int n_nodes)
{
    __shared__ int cnt[128], off[128], fill[128], sc[128];
    int t = threadIdx.x, b = blockIdx.x;
    int s = bucket_start[b], e = bucket_start[b + 1];
    if (t < 128) { cnt[t] = 0; fill[t] = 0; }
    __syncthreads();
    int* scr = scratch + (size_t)b * 8192;
    for (int i = s + t; i < e; i += 256) {
        int p = esort[i];
        scr[i - s] = p;
        atomicAdd(&cnt[(p >> 18) & 127], 1);
    }
    __syncthreads();
    if (t < 128) sc[t] = cnt[t];
    __syncthreads();
    for (int o = 1; o < 128; o <<= 1) {
        int v = (t >= o && t < 128) ? sc[t - o] : 0;
        __syncthreads();
        if (t < 128) sc[t] += v;
        __syncthreads();
    }
    if (t < 128) {
        off[t] = sc[t] - cnt[t];
        int d = b * 128 + t;
        if (d < n_nodes) rowstart[d] = s + off[t];
    }
    __syncthreads();
    for (int i = s + t; i < e; i += 256) {
        int p = scr[i - s];
        int dl = (p >> 18) & 127;
        int pos = s + off[dl] + atomicAdd(&fill[dl], 1);
        esort[pos] = p;
    }
}

// one wave per dst. Quarter-wave q handles edge s+q, s+q+4, ... ; each lane
// holds a float4 channel-quad (c = lane&15). 4 row-loads in flight per wave.
__global__ __launch_bounds__(256) void agg_kernel(
    const float* __restrict__ hin, const int* __restrict__ rowstart,
    const int* __restrict__ esort, float* __restrict__ means, int n_nodes)
{
    int wid = (blockIdx.x * 256 + threadIdx.x) >> 6;
    int lane = threadIdx.x & 63;
    if (wid >= n_nodes) return;
    int q = lane >> 4;       // edge slot within group of 4
    int c = lane & 15;       // channel quad
    int s = rowstart[wid], e = rowstart[wid + 1];

    float a0x=0.f,a0y=0.f,a0z=0.f,a0w=0.f, c0=0.f;
    float a1x=0.f,a1y=0.f,a1z=0.f,a1w=0.f, c1=0.f;
    float a2x=0.f,a2y=0.f,a2z=0.f,a2w=0.f, c2=0.f;

    for (int i = s + q; i < e; i += 4) {
        int p = esort[i];
        int src = p & 0xFFFF;
        int r = (p >> 16) & 3;
        float4 v = *(const float4*)(hin + (size_t)src * 64 + c * 4);
        float m0 = (r == 0) ? 1.f : 0.f;
        float m1 = (r == 1) ? 1.f : 0.f;
        float m2 = (r == 2) ? 1.f : 0.f;
        a0x = fmaf(m0, v.x, a0x); a0y = fmaf(m0, v.y, a0y);
        a0z = fmaf(m0, v.z, a0z); a0w = fmaf(m0, v.w, a0w); c0 += m0;
        a1x = fmaf(m1, v.x, a1x); a1y = fmaf(m1, v.y, a1y);
        a1z = fmaf(m1, v.z, a1z); a1w = fmaf(m1, v.w, a1w); c1 += m1;
        a2x = fmaf(m2, v.x, a2x); a2y = fmaf(m2, v.y, a2y);
        a2z = fmaf(m2, v.z, a2z); a2w = fmaf(m2, v.w, a2w); c2 += m2;
    }
#pragma unroll
    for (int off = 16; off < 64; off <<= 1) {
        a0x += __shfl_xor(a0x, off); a0y += __shfl_xor(a0y, off);
        a0z += __shfl_xor(a0z, off); a0w += __shfl_xor(a0w, off);
        a1x += __shfl_xor(a1x, off); a1y += __shfl_xor(a1y, off);
        a1z += __shfl_xor(a1z, off); a1w += __shfl_xor(a1w, off);
        a2x += __shfl_xor(a2x, off); a2y += __shfl_xor(a2y, off);
        a2z += __shfl_xor(a2z, off); a2w += __shfl_xor(a2w, off);
        c0 += __shfl_xor(c0, off); c1 += __shfl_xor(c1, off);
        c2 += __shfl_xor(c2, off);
    }
    if (q < 3) {
        float ax = (q == 0) ? a0x : (q == 1) ? a1x : a2x;
        float ay = (q == 0) ? a0y : (q == 1) ? a1y : a2y;
        float az = (q == 0) ? a0z : (q == 1) ? a1z : a2z;
        float aw = (q == 0) ? a0w : (q == 1) ? a1w : a2w;
        float cc = (q == 0) ? c0  : (q == 1) ? c1  : c2;
        float inv = 1.f / fmaxf(cc, 1.f);
        float4 m;
        m.x = ax * inv; m.y = ay * inv; m.z = az * inv; m.w = aw * inv;
        *(float4*)(means + (size_t)wid * 192 + q * 64 + c * 4) = m;
    }
}

// thread = (node, j-quad). Combined weight W[256][64] staged in LDS.
__global__ __launch_bounds__(256) void transform_kernel(
    const float* __restrict__ hin, const float* __restrict__ means,
    const float* __restrict__ wroot, const float* __restrict__ wrel,
    const float* __restrict__ bias, float* __restrict__ hout, int n_nodes)
{
    __shared__ float wsh[256 * 64];   // 64 KB -> 2 blocks/CU
    int t = threadIdx.x;
    {
        const float4* src = (const float4*)wroot;
        float4* dst = (float4*)wsh;
#pragma unroll
        for (int i = 0; i < 4; ++i) dst[t + i * 256] = src[t + i * 256];
        src = (const float4*)wrel;
        dst = (float4*)(wsh + 4096);
#pragma unroll
        for (int i = 0; i < 12; ++i) dst[t + i * 256] = src[t + i * 256];
    }
    __syncthreads();

    int gt = blockIdx.x * 256 + t;
    int n = gt >> 4, q = gt & 15;
    if (n >= n_nodes) return;

    float4 b = *(const float4*)(bias + q * 4);
    float acc0 = b.x, acc1 = b.y, acc2 = b.z, acc3 = b.w;

    const float* hv = hin + (size_t)n * 64;
#pragma unroll 4
    for (int k4 = 0; k4 < 16; ++k4) {
        float4 v = *(const float4*)(hv + k4 * 4);
        float vv[4] = {v.x, v.y, v.z, v.w};
#pragma unroll
        for (int i = 0; i < 4; ++i) {
            float4 w = *(const float4*)(wsh + (k4 * 4 + i) * 64 + q * 4);
            acc0 = fmaf(vv[i], w.x, acc0);
            acc1 = fmaf(vv[i], w.y, acc1);
            acc2 = fmaf(vv[i], w.z, acc2);
            acc3 = fmaf(vv[i], w.w, acc3);
        }
    }
    const float* mv = means + (size_t)n * 192;
#pragma unroll 4
    for (int k4 = 0; k4 < 48; ++k4) {
        float4 v = *(const float4*)(mv + k4 * 4);
        float vv[4] = {v.x, v.y, v.z, v.w};
#pragma unroll
        for (int i = 0; i < 4; ++i) {
            float4 w = *(const float4*)(wsh + (64 + k4 * 4 + i) * 64 + q * 4);
            acc0 = fmaf(vv[i], w.x, acc0);
            acc1 = fmaf(vv[i], w.y, acc1);
            acc2 = fmaf(vv[i], w.z, acc2);
            acc3 = fmaf(vv[i], w.w, acc3);
        }
    }
    float4 o;
    o.x = fmaxf(acc0, 0.f); o.y = fmaxf(acc1, 0.f);
    o.z = fmaxf(acc2, 0.f); o.w = fmaxf(acc3, 0.f);
    *(float4*)(hout + (size_t)n * 64 + q * 4) = o;
}

// wave per graph: batch is sorted -> binary-search bounds, mean, then 64->2 head
__global__ __launch_bounds__(256) void pool_kernel(
    const float* __restrict__ h2, const int* __restrict__ batch,
    const float* __restrict__ linw, const float* __restrict__ linb,
    float* __restrict__ out, int n_nodes, int n_graphs)
{
    int wid = (blockIdx.x * 256 + threadIdx.x) >> 6;
    int lane = threadIdx.x & 63;
    if (wid >= n_graphs) return;
    int g = wid;
    int lo = 0, hi = n_nodes;
    while (lo < hi) { int mid = (lo + hi) >> 1; if (batch[mid] < g) lo = mid + 1; else hi = mid; }
    int s = lo;
    lo = 0; hi = n_nodes;
    while (lo < hi) { int mid = (lo + hi) >> 1; if (batch[mid] < g + 1) lo = mid + 1; else hi = mid; }
    int e = lo;
    float sum = 0.f;
    for (int n = s; n < e; ++n) sum += h2[(size_t)n * 64 + lane];
    float mean = sum / (float)max(e - s, 1);
    float d0 = mean * linw[lane * 2 + 0];
    float d1 = mean * linw[lane * 2 + 1];
    for (int off = 32; off > 0; off >>= 1) {
        d0 += __shfl_down(d0, off);
        d1 += __shfl_down(d1, off);
    }
    if (lane == 0) {
        out[g * 2 + 0] = d0 + linb[0];
        out[g * 2 + 1] = d1 + linb[1];
    }
}

extern "C" void kernel_launch(void* const* d_in, const int* in_sizes, int n_in,
                              void* d_out, int out_size, void* d_ws, size_t ws_size,
                              hipStream_t stream)
{
    const int*   x      = (const int*)d_in[0];
    const int*   ei     = (const int*)d_in[1];
    const int*   et     = (const int*)d_in[2];
    const int*   batch  = (const int*)d_in[3];
    const float* emb    = (const float*)d_in[4];
    const float* w1rel  = (const float*)d_in[5];
    const float* w1root = (const float*)d_in[6];
    const float* b1     = (const float*)d_in[7];
    const float* w2rel  = (const float*)d_in[8];
    const float* w2root = (const float*)d_in[9];
    const float* b2     = (const float*)d_in[10];
    const float* linw   = (const float*)d_in[11];
    const float* linb   = (const float*)d_in[12];
    float* out = (float*)d_out;

    const int N = in_sizes[0];        // 50000
    const int E = in_sizes[2];        // 1250000
    const int G = out_size / 2;       // 512
    const int NBKT = (N + 127) >> 7;  // 391 buckets of 128 dsts

    // workspace layout (~70 MB)
    float* hA        = (float*)d_ws;                     // [N][64]
    float* hB        = hA + (size_t)N * 64;              // [N][64]
    float* means     = hB + (size_t)N * 64;              // [N][192]; head doubles as k4 scratch (12.5 MB < 38.4 MB)
    int*   esort     = (int*)(means + (size_t)N * 192);  // [E]
    int*   rowstart  = esort + E;                        // [N+1]
    int*   bucket_count = rowstart + (N + 1);            // [512] (zeroed)
    int*   bucket_fill  = bucket_count + 512;            // [512] (zeroed)
    int*   bucket_start = bucket_fill + 512;             // [513]

    hipMemsetAsync(bucket_count, 0, (size_t)1024 * sizeof(int), stream);

    embed_kernel<<<(N * 16 + 255) / 256, 256, 0, stream>>>(x, emb, hA, N);

    int per_block = (E + 255) / 256;
    bucket_count_kernel<<<256, 256, 0, stream>>>(ei, bucket_count, E, NBKT, per_block);
    scan_buckets_kernel<<<1, 512, 0, stream>>>(bucket_count, bucket_start, rowstart, NBKT, E, N);
    bucket_scatter_kernel<<<(E + 8191) / 8192, 256, 0, stream>>>(ei, et, bucket_start, bucket_fill, esort, E, NBKT);
    bucket_sort_kernel<<<NBKT, 256, 0, stream>>>(bucket_start, esort, (int*)means, rowstart, N);

    int aggBlocks = (N * 64 + 255) / 256;   // one wave per dst
    agg_kernel<<<aggBlocks, 256, 0, stream>>>(hA, rowstart, esort, means, N);
    transform_kernel<<<(N * 16 + 255) / 256, 256, 0, stream>>>(hA, means, w1root, w1rel, b1, hB, N);
    agg_kernel<<<aggBlocks, 256, 0, stream>>>(hB, rowstart, esort, means, N);
    transform_kernel<<<(N * 16 + 255) / 256, 256, 0, stream>>>(hB, means, w2root, w2rel, b2, hA, N);

    pool_kernel<<<(G * 64 + 255) / 256, 256, 0, stream>>>(hA, batch, linw, linb, out, N, G);
}

// Round 5
// 360.697 us; speedup vs baseline: 2.1433x; 1.0724x over previous
//
#include <hip/hip_runtime.h>

// h0[n][k] = (x[n]==0) ? 0 : emb[x[n]][k]   (padding_idx = 0), float4 per thread
__global__ __launch_bounds__(256) void embed_kernel(
    const int* __restrict__ x, const float* __restrict__ emb,
    float* __restrict__ h0, int n_nodes)
{
    int t = blockIdx.x * 256 + threadIdx.x;
    if (t >= n_nodes * 16) return;
    int n = t >> 4, q = t & 15;
    int xv = x[n];
    float4 v = {0.f, 0.f, 0.f, 0.f};
    if (xv != 0) v = *(const float4*)(emb + (size_t)xv * 64 + q * 4);
    *(float4*)(h0 + (size_t)n * 64 + q * 4) = v;
}

// ---- CSR build: two-level bucket sort (bucket = dst>>7, 128 dsts/bucket) ----

__global__ __launch_bounds__(256) void bucket_count_kernel(
    const int* __restrict__ ei, int* __restrict__ bucket_count,
    int n_edges, int n_bkt, int per_block)
{
    __shared__ int cnt[512];
    int t = threadIdx.x;
    for (int i = t; i < n_bkt; i += 256) cnt[i] = 0;
    __syncthreads();
    int lo = blockIdx.x * per_block;
    int hi = min(n_edges, lo + per_block);
    for (int e = lo + t; e < hi; e += 256)
        atomicAdd(&cnt[ei[n_edges + e] >> 7], 1);
    __syncthreads();
    for (int i = t; i < n_bkt; i += 256)
        if (cnt[i]) atomicAdd(&bucket_count[i], cnt[i]);
}

__global__ __launch_bounds__(512) void scan_buckets_kernel(
    const int* __restrict__ bucket_count, int* __restrict__ bucket_start,
    int* __restrict__ rowstart, int n_bkt, int n_edges, int n_nodes)
{
    __shared__ int part[512];
    int t = threadIdx.x;
    part[t] = (t < n_bkt) ? bucket_count[t] : 0;
    __syncthreads();
    for (int off = 1; off < 512; off <<= 1) {
        int v = (t >= off) ? part[t - off] : 0;
        __syncthreads();
        part[t] += v;
        __syncthreads();
    }
    if (t == 0) { bucket_start[0] = 0; rowstart[n_nodes] = n_edges; }
    if (t < n_bkt) bucket_start[t + 1] = part[t];
}

// 8192 edges/block: reserve one contiguous run per (block,bucket) via a single
// global atomic; entries src(16) | type(2)<<16 | (dst&127)<<18, block-private
// dense writes (no cross-XCD line thrash).
__global__ __launch_bounds__(256) void bucket_scatter_kernel(
    const int* __restrict__ ei, const int* __restrict__ et,
    const int* __restrict__ bucket_start, int* __restrict__ bucket_fill,
    int* __restrict__ esort, int n_edges, int n_bkt)
{
    __shared__ int cnt[512], gbase[512], fill2[512];
    const int EPT = 32;
    int t = threadIdx.x;
    int base = blockIdx.x * 256 * EPT;
    for (int i = t; i < n_bkt; i += 256) { cnt[i] = 0; fill2[i] = 0; }
    __syncthreads();
    int pay[EPT], bk[EPT];
#pragma unroll
    for (int i = 0; i < EPT; ++i) {
        int e = base + i * 256 + t;
        bk[i] = -1;
        if (e < n_edges) {
            int s = ei[e], d = ei[n_edges + e], r = et[e];
            int b = d >> 7;
            pay[i] = s | (r << 16) | ((d & 127) << 18);
            bk[i] = b;
            atomicAdd(&cnt[b], 1);
        }
    }
    __syncthreads();
    for (int i = t; i < n_bkt; i += 256)
        if (cnt[i]) gbase[i] = bucket_start[i] + atomicAdd(&bucket_fill[i], cnt[i]);
    __syncthreads();
#pragma unroll
    for (int i = 0; i < EPT; ++i) {
        if (bk[i] >= 0) {
            int pos = gbase[bk[i]] + atomicAdd(&fill2[bk[i]], 1);
            esort[pos] = pay[i];
        }
    }
}

// one block per bucket: LDS counting-sort by dst-within-bucket (128 bins),
// emits rowstart[dst] from the scan.
__global__ __launch_bounds__(256) void bucket_sort_kernel(
    const int* __restrict__ bucket_start, int* __restrict__ esort,
    int* __restrict__ scratch, int* __restrict__ rowstart, int n_nodes)
{
    __shared__ int cnt[128], off[128], fill[128], sc[128];
    int t = threadIdx.x, b = blockIdx.x;
    int s = bucket_start[b], e = bucket_start[b + 1];
    if (t < 128) { cnt[t] = 0; fill[t] = 0; }
    __syncthreads();
    int* scr = scratch + (size_t)b * 8192;
    for (int i = s + t; i < e; i += 256) {
        int p = esort[i];
        scr[i - s] = p;
        atomicAdd(&cnt[(p >> 18) & 127], 1);
    }
    __syncthreads();
    if (t < 128) sc[t] = cnt[t];
    __syncthreads();
    for (int o = 1; o < 128; o <<= 1) {
        int v = (t >= o && t < 128) ? sc[t - o] : 0;
        __syncthreads();
        if (t < 128) sc[t] += v;
        __syncthreads();
    }
    if (t < 128) {
        off[t] = sc[t] - cnt[t];
        int d = b * 128 + t;
        if (d < n_nodes) rowstart[d] = s + off[t];
    }
    __syncthreads();
    for (int i = s + t; i < e; i += 256) {
        int p = scr[i - s];
        int dl = (p >> 18) & 127;
        int pos = s + off[dl] + atomicAdd(&fill[dl], 1);
        esort[pos] = p;
    }
}

// one wave per dst. Quarter-wave q handles edge s+q, s+q+4, ... ; each lane
// holds a float4 channel-quad (c = lane&15). 4 row-loads in flight per wave.
__global__ __launch_bounds__(256) void agg_kernel(
    const float* __restrict__ hin, const int* __restrict__ rowstart,
    const int* __restrict__ esort, float* __restrict__ means, int n_nodes)
{
    int wid = (blockIdx.x * 256 + threadIdx.x) >> 6;
    int lane = threadIdx.x & 63;
    if (wid >= n_nodes) return;
    int q = lane >> 4;       // edge slot within group of 4
    int c = lane & 15;       // channel quad
    int s = rowstart[wid], e = rowstart[wid + 1];

    float a0x=0.f,a0y=0.f,a0z=0.f,a0w=0.f, c0=0.f;
    float a1x=0.f,a1y=0.f,a1z=0.f,a1w=0.f, c1=0.f;
    float a2x=0.f,a2y=0.f,a2z=0.f,a2w=0.f, c2=0.f;

    for (int i = s + q; i < e; i += 4) {
        int p = esort[i];
        int src = p & 0xFFFF;
        int r = (p >> 16) & 3;
        float4 v = *(const float4*)(hin + (size_t)src * 64 + c * 4);
        float m0 = (r == 0) ? 1.f : 0.f;
        float m1 = (r == 1) ? 1.f : 0.f;
        float m2 = (r == 2) ? 1.f : 0.f;
        a0x = fmaf(m0, v.x, a0x); a0y = fmaf(m0, v.y, a0y);
        a0z = fmaf(m0, v.z, a0z); a0w = fmaf(m0, v.w, a0w); c0 += m0;
        a1x = fmaf(m1, v.x, a1x); a1y = fmaf(m1, v.y, a1y);
        a1z = fmaf(m1, v.z, a1z); a1w = fmaf(m1, v.w, a1w); c1 += m1;
        a2x = fmaf(m2, v.x, a2x); a2y = fmaf(m2, v.y, a2y);
        a2z = fmaf(m2, v.z, a2z); a2w = fmaf(m2, v.w, a2w); c2 += m2;
    }
#pragma unroll
    for (int off = 16; off < 64; off <<= 1) {
        a0x += __shfl_xor(a0x, off); a0y += __shfl_xor(a0y, off);
        a0z += __shfl_xor(a0z, off); a0w += __shfl_xor(a0w, off);
        a1x += __shfl_xor(a1x, off); a1y += __shfl_xor(a1y, off);
        a1z += __shfl_xor(a1z, off); a1w += __shfl_xor(a1w, off);
        a2x += __shfl_xor(a2x, off); a2y += __shfl_xor(a2y, off);
        a2z += __shfl_xor(a2z, off); a2w += __shfl_xor(a2w, off);
        c0 += __shfl_xor(c0, off); c1 += __shfl_xor(c1, off);
        c2 += __shfl_xor(c2, off);
    }
    if (q < 3) {
        float ax = (q == 0) ? a0x : (q == 1) ? a1x : a2x;
        float ay = (q == 0) ? a0y : (q == 1) ? a1y : a2y;
        float az = (q == 0) ? a0z : (q == 1) ? a1z : a2z;
        float aw = (q == 0) ? a0w : (q == 1) ? a1w : a2w;
        float cc = (q == 0) ? c0  : (q == 1) ? c1  : c2;
        float inv = 1.f / fmaxf(cc, 1.f);
        float4 m;
        m.x = ax * inv; m.y = ay * inv; m.z = az * inv; m.w = aw * inv;
        *(float4*)(means + (size_t)wid * 192 + q * 64 + c * 4) = m;
    }
}

// thread = (4-node group, j-quad). W[256][64] in LDS; each ds_read_b128 of a
// W row-quad is amortized over 4 nodes (16 FMAs) -> LDS pipe no longer the
// bottleneck (3072 cyc LDS vs 8192 cyc VALU per wave).
__global__ __launch_bounds__(256) void transform_kernel(
    const float* __restrict__ hin, const float* __restrict__ means,
    const float* __restrict__ wroot, const float* __restrict__ wrel,
    const float* __restrict__ bias, float* __restrict__ hout, int n_nodes)
{
    __shared__ float wsh[256 * 64];   // 64 KB -> 2 blocks/CU
    int t = threadIdx.x;
    {
        const float4* src = (const float4*)wroot;
        float4* dst = (float4*)wsh;
#pragma unroll
        for (int i = 0; i < 4; ++i) dst[t + i * 256] = src[t + i * 256];
        src = (const float4*)wrel;
        dst = (float4*)(wsh + 4096);
#pragma unroll
        for (int i = 0; i < 12; ++i) dst[t + i * 256] = src[t + i * 256];
    }
    __syncthreads();

    int gt = blockIdx.x * 256 + t;
    int g = gt >> 4, q = gt & 15;
    int n0 = g * 4;
    if (n0 >= n_nodes) return;

    float4 b = *(const float4*)(bias + q * 4);
    float acc0x=b.x, acc0y=b.y, acc0z=b.z, acc0w=b.w;
    float acc1x=b.x, acc1y=b.y, acc1z=b.z, acc1w=b.w;
    float acc2x=b.x, acc2y=b.y, acc2z=b.z, acc2w=b.w;
    float acc3x=b.x, acc3y=b.y, acc3z=b.z, acc3w=b.w;

    const float* hv = hin + (size_t)n0 * 64;
#pragma unroll 2
    for (int k4 = 0; k4 < 16; ++k4) {
        float4 va = *(const float4*)(hv +   0 + k4 * 4);
        float4 vb = *(const float4*)(hv +  64 + k4 * 4);
        float4 vc = *(const float4*)(hv + 128 + k4 * 4);
        float4 vd = *(const float4*)(hv + 192 + k4 * 4);
#pragma unroll
        for (int kk = 0; kk < 4; ++kk) {
            float4 w = *(const float4*)(wsh + (k4 * 4 + kk) * 64 + q * 4);
            float a = kk==0?va.x:kk==1?va.y:kk==2?va.z:va.w;
            float bb= kk==0?vb.x:kk==1?vb.y:kk==2?vb.z:vb.w;
            float c = kk==0?vc.x:kk==1?vc.y:kk==2?vc.z:vc.w;
            float d = kk==0?vd.x:kk==1?vd.y:kk==2?vd.z:vd.w;
            acc0x=fmaf(a,w.x,acc0x); acc0y=fmaf(a,w.y,acc0y); acc0z=fmaf(a,w.z,acc0z); acc0w=fmaf(a,w.w,acc0w);
            acc1x=fmaf(bb,w.x,acc1x); acc1y=fmaf(bb,w.y,acc1y); acc1z=fmaf(bb,w.z,acc1z); acc1w=fmaf(bb,w.w,acc1w);
            acc2x=fmaf(c,w.x,acc2x); acc2y=fmaf(c,w.y,acc2y); acc2z=fmaf(c,w.z,acc2z); acc2w=fmaf(c,w.w,acc2w);
            acc3x=fmaf(d,w.x,acc3x); acc3y=fmaf(d,w.y,acc3y); acc3z=fmaf(d,w.z,acc3z); acc3w=fmaf(d,w.w,acc3w);
        }
    }
    const float* mv = means + (size_t)n0 * 192;
#pragma unroll 2
    for (int k4 = 0; k4 < 48; ++k4) {
        float4 va = *(const float4*)(mv +   0 + k4 * 4);
        float4 vb = *(const float4*)(mv + 192 + k4 * 4);
        float4 vc = *(const float4*)(mv + 384 + k4 * 4);
        float4 vd = *(const float4*)(mv + 576 + k4 * 4);
#pragma unroll
        for (int kk = 0; kk < 4; ++kk) {
            float4 w = *(const float4*)(wsh + (64 + k4 * 4 + kk) * 64 + q * 4);
            float a = kk==0?va.x:kk==1?va.y:kk==2?va.z:va.w;
            float bb= kk==0?vb.x:kk==1?vb.y:kk==2?vb.z:vb.w;
            float c = kk==0?vc.x:kk==1?vc.y:kk==2?vc.z:vc.w;
            float d = kk==0?vd.x:kk==1?vd.y:kk==2?vd.z:vd.w;
            acc0x=fmaf(a,w.x,acc0x); acc0y=fmaf(a,w.y,acc0y); acc0z=fmaf(a,w.z,acc0z); acc0w=fmaf(a,w.w,acc0w);
            acc1x=fmaf(bb,w.x,acc1x); acc1y=fmaf(bb,w.y,acc1y); acc1z=fmaf(bb,w.z,acc1z); acc1w=fmaf(bb,w.w,acc1w);
            acc2x=fmaf(c,w.x,acc2x); acc2y=fmaf(c,w.y,acc2y); acc2z=fmaf(c,w.z,acc2z); acc2w=fmaf(c,w.w,acc2w);
            acc3x=fmaf(d,w.x,acc3x); acc3y=fmaf(d,w.y,acc3y); acc3z=fmaf(d,w.z,acc3z); acc3w=fmaf(d,w.w,acc3w);
        }
    }
    float* o = hout + (size_t)n0 * 64 + q * 4;
    float4 r0 = {fmaxf(acc0x,0.f), fmaxf(acc0y,0.f), fmaxf(acc0z,0.f), fmaxf(acc0w,0.f)};
    float4 r1 = {fmaxf(acc1x,0.f), fmaxf(acc1y,0.f), fmaxf(acc1z,0.f), fmaxf(acc1w,0.f)};
    float4 r2 = {fmaxf(acc2x,0.f), fmaxf(acc2y,0.f), fmaxf(acc2z,0.f), fmaxf(acc2w,0.f)};
    float4 r3 = {fmaxf(acc3x,0.f), fmaxf(acc3y,0.f), fmaxf(acc3z,0.f), fmaxf(acc3w,0.f)};
    *(float4*)(o +   0) = r0;
    *(float4*)(o +  64) = r1;
    *(float4*)(o + 128) = r2;
    *(float4*)(o + 192) = r3;
}

// wave per graph: batch is sorted -> binary-search bounds, mean, then 64->2 head
__global__ __launch_bounds__(256) void pool_kernel(
    const float* __restrict__ h2, const int* __restrict__ batch,
    const float* __restrict__ linw, const float* __restrict__ linb,
    float* __restrict__ out, int n_nodes, int n_graphs)
{
    int wid = (blockIdx.x * 256 + threadIdx.x) >> 6;
    int lane = threadIdx.x & 63;
    if (wid >= n_graphs) return;
    int g = wid;
    int lo = 0, hi = n_nodes;
    while (lo < hi) { int mid = (lo + hi) >> 1; if (batch[mid] < g) lo = mid + 1; else hi = mid; }
    int s = lo;
    lo = 0; hi = n_nodes;
    while (lo < hi) { int mid = (lo + hi) >> 1; if (batch[mid] < g + 1) lo = mid + 1; else hi = mid; }
    int e = lo;
    float sum = 0.f;
    for (int n = s; n < e; ++n) sum += h2[(size_t)n * 64 + lane];
    float mean = sum / (float)max(e - s, 1);
    float d0 = mean * linw[lane * 2 + 0];
    float d1 = mean * linw[lane * 2 + 1];
    for (int off = 32; off > 0; off >>= 1) {
        d0 += __shfl_down(d0, off);
        d1 += __shfl_down(d1, off);
    }
    if (lane == 0) {
        out[g * 2 + 0] = d0 + linb[0];
        out[g * 2 + 1] = d1 + linb[1];
    }
}

extern "C" void kernel_launch(void* const* d_in, const int* in_sizes, int n_in,
                              void* d_out, int out_size, void* d_ws, size_t ws_size,
                              hipStream_t stream)
{
    const int*   x      = (const int*)d_in[0];
    const int*   ei     = (const int*)d_in[1];
    const int*   et     = (const int*)d_in[2];
    const int*   batch  = (const int*)d_in[3];
    const float* emb    = (const float*)d_in[4];
    const float* w1rel  = (const float*)d_in[5];
    const float* w1root = (const float*)d_in[6];
    const float* b1     = (const float*)d_in[7];
    const float* w2rel  = (const float*)d_in[8];
    const float* w2root = (const float*)d_in[9];
    const float* b2     = (const float*)d_in[10];
    const float* linw   = (const float*)d_in[11];
    const float* linb   = (const float*)d_in[12];
    float* out = (float*)d_out;

    const int N = in_sizes[0];        // 50000
    const int E = in_sizes[2];        // 1250000
    const int G = out_size / 2;       // 512
    const int NBKT = (N + 127) >> 7;  // 391 buckets of 128 dsts

    // workspace layout (~70 MB)
    float* hA        = (float*)d_ws;                     // [N][64]
    float* hB        = hA + (size_t)N * 64;              // [N][64]
    float* means     = hB + (size_t)N * 64;              // [N][192]; head doubles as sort scratch
    int*   esort     = (int*)(means + (size_t)N * 192);  // [E]
    int*   rowstart  = esort + E;                        // [N+1]
    int*   bucket_count = rowstart + (N + 1);            // [512] (zeroed)
    int*   bucket_fill  = bucket_count + 512;            // [512] (zeroed)
    int*   bucket_start = bucket_fill + 512;             // [513]

    hipMemsetAsync(bucket_count, 0, (size_t)1024 * sizeof(int), stream);

    embed_kernel<<<(N * 16 + 255) / 256, 256, 0, stream>>>(x, emb, hA, N);

    int per_block = (E + 255) / 256;
    bucket_count_kernel<<<256, 256, 0, stream>>>(ei, bucket_count, E, NBKT, per_block);
    scan_buckets_kernel<<<1, 512, 0, stream>>>(bucket_count, bucket_start, rowstart, NBKT, E, N);
    bucket_scatter_kernel<<<(E + 8191) / 8192, 256, 0, stream>>>(ei, et, bucket_start, bucket_fill, esort, E, NBKT);
    bucket_sort_kernel<<<NBKT, 256, 0, stream>>>(bucket_start, esort, (int*)means, rowstart, N);

    int aggBlocks = (N * 64 + 255) / 256;   // one wave per dst
    int tfBlocks  = ((N + 3) / 4 * 16 + 255) / 256;
    agg_kernel<<<aggBlocks, 256, 0, stream>>>(hA, rowstart, esort, means, N);
    transform_kernel<<<tfBlocks, 256, 0, stream>>>(hA, means, w1root, w1rel, b1, hB, N);
    agg_kernel<<<aggBlocks, 256, 0, stream>>>(hB, rowstart, esort, means, N);
    transform_kernel<<<tfBlocks, 256, 0, stream>>>(hB, means, w2root, w2rel, b2, hA, N);

    pool_kernel<<<(G * 64 + 255) / 256, 256, 0, stream>>>(hA, batch, linw, linb, out, N, G);
}